// Round 8
// baseline (256.592 us; speedup 1.0000x reference)
//
#include <hip/hip_runtime.h>
#include <hip/hip_bf16.h>

// CrossMultiHeadAttention: B=4, N=M=2048, D=1024, H=16, hd=64, f32 in/out.
// bf16 pipeline: fused cvt -> Q-GEMM(exp2-scaled) / K-GEMM / V-GEMM(transposed epi)
// -> flash attn (prefetch-depth-2 counted-vmcnt pipeline, XCD-affine blocks,
//    no-max softmax, P in regs) -> out GEMM.

typedef __attribute__((ext_vector_type(8))) short bf16x8;
typedef __attribute__((ext_vector_type(4))) float f32x4;
typedef __attribute__((ext_vector_type(16))) float f32x16;
typedef __attribute__((ext_vector_type(4))) unsigned short u16x4;
typedef __attribute__((ext_vector_type(4))) unsigned int u32x4;

#define SEQ 2048
#define H_ 16

static __device__ __forceinline__ unsigned short f2bf(float f) {
  unsigned int u = __float_as_uint(f);
  u += 0x7fffu + ((u >> 16) & 1u);
  return (unsigned short)(u >> 16);
}

static __device__ __forceinline__ void gload16(const void* g, void* l) {
  __builtin_amdgcn_global_load_lds((const __attribute__((address_space(1))) void*)g,
                                   (__attribute__((address_space(3))) void*)l, 16, 0, 0);
}

// One launch converts all six f32 inputs to bf16.
__global__ __launch_bounds__(256) void k_cvt_all(const float* __restrict__ x, const float* __restrict__ e,
    const float* __restrict__ wq, const float* __restrict__ wk,
    const float* __restrict__ wv, const float* __restrict__ wo,
    unsigned short* __restrict__ Xb, unsigned short* __restrict__ Eb,
    unsigned short* __restrict__ Wqb, unsigned short* __restrict__ Wkb,
    unsigned short* __restrict__ Wvb, unsigned short* __restrict__ Wob) {
  int i = blockIdx.x * 256 + threadIdx.x;
  const float* src; unsigned short* dst; int off;
  if (i < 2097152)      { src = x;  dst = Xb;  off = i; }
  else if (i < 4194304) { src = e;  dst = Eb;  off = i - 2097152; }
  else if (i < 4456448) { src = wq; dst = Wqb; off = i - 4194304; }
  else if (i < 4718592) { src = wk; dst = Wkb; off = i - 4456448; }
  else if (i < 4980736) { src = wv; dst = Wvb; off = i - 4718592; }
  else                  { src = wo; dst = Wob; off = i - 4980736; }
  float4 v = reinterpret_cast<const float4*>(src)[off];
  u16x4 o;
  o[0] = f2bf(v.x); o[1] = f2bf(v.y); o[2] = f2bf(v.z); o[3] = f2bf(v.w);
  *reinterpret_cast<u16x4*>(dst + (size_t)off * 4) = o;
}

// C = A[R,1024] @ W[1024,1024]^T.
// MODE 0: bf16 out, [B,H,seq,64] head layout (K path).
// MODE 1: f32 out, [R,1024] (final out).
// MODE 2: like 0 but scaled by 0.125*log2(e) (Q path).
// MODE 3: bf16 out, transposed head layout [B,H,64,seq] (V path -> Vt direct).
template<int MODE>
__global__ __launch_bounds__(256) void k_gemm(const unsigned short* __restrict__ A,
                                              const unsigned short* __restrict__ W,
                                              void* __restrict__ out) {
  __shared__ __align__(16) unsigned short As[128 * 32];
  __shared__ __align__(16) unsigned short Bs[128 * 32];
  const int tid = threadIdx.x, lane = tid & 63, w = tid >> 6;
  const int col0 = blockIdx.x * 128, row0 = blockIdx.y * 128;
  const int wr = w >> 1, wc = w & 1;
  f32x4 acc[4][4];
  for (int i = 0; i < 4; ++i)
    for (int j = 0; j < 4; ++j)
      for (int e = 0; e < 4; ++e) acc[i][j][e] = 0.f;
  const unsigned short* Ag[2];
  const unsigned short* Wg[2];
  unsigned short* Al[2];
  unsigned short* Bl[2];
  for (int p = 0; p < 2; ++p) {
    int ci = p * 4 + w;
    int eo = ci * 512 + lane * 8;
    int r = eo >> 5, c = eo & 31;
    Ag[p] = A + (size_t)(row0 + r) * 1024 + c;
    Wg[p] = W + (size_t)(col0 + r) * 1024 + c;
    Al[p] = &As[ci * 512];
    Bl[p] = &Bs[ci * 512];
  }
  const int fr = lane & 15, ko = (lane >> 4) * 8;
  for (int k0 = 0; k0 < 1024; k0 += 32) {
    __syncthreads();
    for (int p = 0; p < 2; ++p) {
      gload16(Ag[p] + k0, Al[p]);
      gload16(Wg[p] + k0, Bl[p]);
    }
    __syncthreads();
    bf16x8 af[4], bfr[4];
    for (int mi = 0; mi < 4; ++mi)
      af[mi] = *(const bf16x8*)&As[(wr * 64 + mi * 16 + fr) * 32 + ko];
    for (int ni = 0; ni < 4; ++ni)
      bfr[ni] = *(const bf16x8*)&Bs[(wc * 64 + ni * 16 + fr) * 32 + ko];
    for (int mi = 0; mi < 4; ++mi)
      for (int ni = 0; ni < 4; ++ni)
        acc[mi][ni] = __builtin_amdgcn_mfma_f32_16x16x32_bf16(af[mi], bfr[ni], acc[mi][ni], 0, 0, 0);
  }
  if (MODE == 3) {
    // transposed write: Vt[((b*16+h)*64 + c)*2048 + n], j -> contiguous n
    for (int mi = 0; mi < 4; ++mi)
      for (int ni = 0; ni < 4; ++ni) {
        int r0 = row0 + wr * 64 + mi * 16 + (lane >> 4) * 4;
        int o = col0 + wc * 64 + ni * 16 + (lane & 15);
        int b = r0 >> 11, n0 = r0 & (SEQ - 1);
        int h = o >> 6, c = o & 63;
        u16x4 o4;
        for (int j = 0; j < 4; ++j) o4[j] = f2bf(acc[mi][ni][j]);
        *(u16x4*)&((unsigned short*)out)[(((size_t)(b * H_ + h)) * 64 + c) * SEQ + n0] = o4;
      }
  } else {
    for (int mi = 0; mi < 4; ++mi)
      for (int ni = 0; ni < 4; ++ni)
        for (int j = 0; j < 4; ++j) {
          int r = row0 + wr * 64 + mi * 16 + (lane >> 4) * 4 + j;
          int o = col0 + wc * 64 + ni * 16 + (lane & 15);
          float val = acc[mi][ni][j];
          if (MODE == 2) val *= 0.18033688f;   // 0.125 * log2(e)
          if (MODE == 0 || MODE == 2) {
            int b = r >> 11, n = r & (SEQ - 1);
            int h = o >> 6, c = o & 63;
            ((unsigned short*)out)[(((size_t)(b * H_ + h)) * SEQ + n) * 64 + c] = f2bf(val);
          } else {
            ((float*)out)[(size_t)r * 1024 + o] = val;
          }
        }
  }
}

static __device__ __forceinline__ int swzaddr(int row, int colb) {
  return row * 128 + (colb ^ ((row & 7) << 4));
}

// Flash attention, no-max softmax (Q pre-scaled to exp2 domain).
// Q,K in [B,H,seq,64]; Vt in [B,H,64,seq]; CTX [B*N,1024] bf16.
// 4 waves x 32 q-rows; KV tiles of 64; TRIPLE buffer, prefetch depth 2.
// Counted s_waitcnt vmcnt(4) + raw s_barrier: only the oldest stage must
// retire at each tile; the next stage's 4 loads stay in flight across the
// barrier (T3/T4). 1-D grid with XCD-affine (bh,qt) decode: each XCD sees
// only 8 heads -> K/V working set = 4 MB = its L2.
__global__ __launch_bounds__(256) void k_attn(const unsigned short* __restrict__ Qh,
                                              const unsigned short* __restrict__ Kh,
                                              const unsigned short* __restrict__ Vtg,
                                              unsigned short* __restrict__ CTX) {
  __shared__ __align__(16) char lds[3 * 16384];
  const int tid = threadIdx.x, lane = tid & 63, w = tid >> 6;
  const int hi = lane >> 5, q = lane & 31;
  const int id = blockIdx.x;
  const int bh = (id & 7) * 8 + ((id >> 3) & 7);   // XCD-affine head grouping
  const int qt = id >> 6;
  const size_t kvbase = (size_t)bh * (SEQ * 64);
  const size_t qrow = (size_t)bh * SEQ + qt * 128 + w * 32 + q;
  bf16x8 qf[4];
#pragma unroll
  for (int c = 0; c < 4; ++c)
    qf[c] = *(const bf16x8*)&Qh[qrow * 64 + c * 16 + hi * 8];
  f32x16 oacc0, oacc1, fzero;
#pragma unroll
  for (int r = 0; r < 16; ++r) { oacc0[r] = 0.f; oacc1[r] = 0.f; fzero[r] = 0.f; }
  float l_run = 0.f;

  // staging: 512 16B chunks per 8KB tile; thread handles chunks tid, tid+256.
  // LDS linear; global source pre-swizzled so reads use colb ^ ((row&7)<<4).
  size_t koff[2], voff[2];
  int ldso[2];
#pragma unroll
  for (int h = 0; h < 2; ++h) {
    int c = tid + h * 256;
    int row = c >> 3, pb = (c & 7) << 4;
    int ge = (pb ^ ((row & 7) << 4)) >> 1;
    koff[h] = (size_t)row * 64 + ge;     // + t*4096
    voff[h] = (size_t)row * SEQ + ge;    // + t*64
    ldso[h] = c * 16;
  }

#define STAGE(T, BUFO)                                          \
  {                                                             \
    _Pragma("unroll")                                           \
    for (int h = 0; h < 2; ++h) {                               \
      gload16(Kh + kvbase + (size_t)(T) * 4096 + koff[h], lds + (BUFO) + ldso[h]);        \
      gload16(Vtg + kvbase + (size_t)(T) * 64 + voff[h], lds + (BUFO) + 8192 + ldso[h]);  \
    }                                                           \
  }

  STAGE(0, 0);
  STAGE(1, 16384);

  int b_prev = 32768, b_cur = 0, b_nxt = 16384;  // stage target = b_prev ((t+2)%3)

  for (int t = 0; t < 32; ++t) {
    // Oldest in-flight stage (tile t, 4 loads/thread) must retire; tile t+1's
    // 4 loads stay in flight across the barrier.
    if (t < 31) asm volatile("s_waitcnt vmcnt(4)" ::: "memory");
    else        asm volatile("s_waitcnt vmcnt(0)" ::: "memory");
    __builtin_amdgcn_s_barrier();
    asm volatile("" ::: "memory");
    __builtin_amdgcn_sched_barrier(0);

    if (t + 2 < 32) STAGE(t + 2, b_prev);

    char* Kb = lds + b_cur;
    char* Vb = lds + b_cur + 8192;

    // QK^T (swapped): s[half] = S^T[key][q], already in exp2 domain
    f32x16 s0, s1;
    __builtin_amdgcn_s_setprio(1);
    {
      bf16x8 kf0 = *(const bf16x8*)(Kb + swzaddr(q, 0 * 32 + hi * 16));
      bf16x8 kf1 = *(const bf16x8*)(Kb + swzaddr(32 + q, 0 * 32 + hi * 16));
      s0 = __builtin_amdgcn_mfma_f32_32x32x16_bf16(kf0, qf[0], fzero, 0, 0, 0);
      s1 = __builtin_amdgcn_mfma_f32_32x32x16_bf16(kf1, qf[0], fzero, 0, 0, 0);
    }
#pragma unroll
    for (int c = 1; c < 4; ++c) {
      bf16x8 kf0 = *(const bf16x8*)(Kb + swzaddr(q, c * 32 + hi * 16));
      bf16x8 kf1 = *(const bf16x8*)(Kb + swzaddr(32 + q, c * 32 + hi * 16));
      s0 = __builtin_amdgcn_mfma_f32_32x32x16_bf16(kf0, qf[c], s0, 0, 0, 0);
      s1 = __builtin_amdgcn_mfma_f32_32x32x16_bf16(kf1, qf[c], s1, 0, 0, 0);
    }
    __builtin_amdgcn_s_setprio(0);

    bf16x8 pfrag[4];

#define SOFT_PACK(SREG, FA, FB)                                               \
    {                                                                         \
      float pa[16];                                                           \
      _Pragma("unroll")                                                       \
      for (int r = 0; r < 16; ++r) pa[r] = exp2f(SREG[r]);                    \
      float l0 = 0.f, l1 = 0.f, l2 = 0.f, l3 = 0.f;                           \
      _Pragma("unroll")                                                       \
      for (int r = 0; r < 4; ++r) {                                           \
        l0 += pa[r]; l1 += pa[4 + r]; l2 += pa[8 + r]; l3 += pa[12 + r];      \
      }                                                                       \
      l_run += (l0 + l1) + (l2 + l3);                                         \
      unsigned pw[8];                                                         \
      _Pragma("unroll")                                                       \
      for (int i = 0; i < 8; ++i)                                             \
        asm("v_cvt_pk_bf16_f32 %0, %1, %2" : "=v"(pw[i])                      \
            : "v"(pa[2 * i]), "v"(pa[2 * i + 1]));                            \
      asm("v_permlane32_swap_b32 %0, %1" : "+v"(pw[0]), "+v"(pw[2]));         \
      asm("v_permlane32_swap_b32 %0, %1" : "+v"(pw[1]), "+v"(pw[3]));         \
      asm("v_permlane32_swap_b32 %0, %1" : "+v"(pw[4]), "+v"(pw[6]));         \
      asm("v_permlane32_swap_b32 %0, %1" : "+v"(pw[5]), "+v"(pw[7]));         \
      u32x4 fa = { pw[0], pw[1], pw[2], pw[3] };                              \
      u32x4 fb = { pw[4], pw[5], pw[6], pw[7] };                              \
      FA = __builtin_bit_cast(bf16x8, fa);                                    \
      FB = __builtin_bit_cast(bf16x8, fb);                                    \
    }

    SOFT_PACK(s0, pfrag[0], pfrag[1])
    SOFT_PACK(s1, pfrag[2], pfrag[3])
#undef SOFT_PACK

    // PV: ctx^T[d][q] += Vt[d][key] * P^T[key][q]
    __builtin_amdgcn_s_setprio(1);
#pragma unroll
    for (int kk = 0; kk < 4; ++kk) {
      bf16x8 vf0 = *(const bf16x8*)(Vb + swzaddr(q, kk * 32 + hi * 16));
      bf16x8 vf1 = *(const bf16x8*)(Vb + swzaddr(32 + q, kk * 32 + hi * 16));
      oacc0 = __builtin_amdgcn_mfma_f32_32x32x16_bf16(vf0, pfrag[kk], oacc0, 0, 0, 0);
      oacc1 = __builtin_amdgcn_mfma_f32_32x32x16_bf16(vf1, pfrag[kk], oacc1, 0, 0, 0);
    }
    __builtin_amdgcn_s_setprio(0);

    int tmp = b_prev; b_prev = b_cur; b_cur = b_nxt; b_nxt = tmp;
  }
#undef STAGE

  // merge key-halves of the row-sum (hi=0/1 lanes hold complementary halves)
  l_run += __shfl_xor(l_run, 32);

  // epilogue: lane q owns its whole row -> pure per-lane 1/l scale
  const float inv = 1.0f / l_run;
  const int b = bh >> 4, h = bh & 15;
  const size_t orow = ((size_t)b * SEQ + qt * 128 + w * 32 + q) * 1024 + h * 64;
#pragma unroll
  for (int g = 0; g < 4; ++g) {
    u16x4 o0, o1;
#pragma unroll
    for (int j = 0; j < 4; ++j) {
      o0[j] = f2bf(oacc0[g * 4 + j] * inv);
      o1[j] = f2bf(oacc1[g * 4 + j] * inv);
    }
    *(u16x4*)&CTX[orow + g * 8 + hi * 4] = o0;
    *(u16x4*)&CTX[orow + 32 + g * 8 + hi * 4] = o1;
  }
}

extern "C" void kernel_launch(void* const* d_in, const int* in_sizes, int n_in,
                              void* d_out, int out_size, void* d_ws, size_t ws_size,
                              hipStream_t stream) {
  const float* x  = (const float*)d_in[0];
  const float* e  = (const float*)d_in[1];
  const float* wq = (const float*)d_in[2];
  const float* wk = (const float*)d_in[3];
  const float* wv = (const float*)d_in[4];
  const float* wo = (const float*)d_in[5];
  unsigned short* Xb  = (unsigned short*)d_ws;
  unsigned short* Eb  = Xb + 8388608;
  unsigned short* Wqb = Eb + 8388608;
  unsigned short* Wkb = Wqb + 1048576;
  unsigned short* Wvb = Wkb + 1048576;
  unsigned short* Wob = Wvb + 1048576;
  unsigned short* Qb  = Wob + 1048576;
  unsigned short* Kb  = Qb + 8388608;
  unsigned short* Vtg = Kb + 8388608;   // V-GEMM writes transposed layout directly
  unsigned short* Cb  = Vtg + 8388608;

  k_cvt_all<<<20480, 256, 0, stream>>>(x, e, wq, wk, wv, wo, Xb, Eb, Wqb, Wkb, Wvb, Wob);

  dim3 gg(8, 64);
  k_gemm<2><<<gg, 256, 0, stream>>>(Xb, Wqb, Qb);   // Q, exp2-domain pre-scale
  k_gemm<0><<<gg, 256, 0, stream>>>(Eb, Wkb, Kb);
  k_gemm<3><<<gg, 256, 0, stream>>>(Eb, Wvb, Vtg);  // V, transposed epilogue

  k_attn<<<1024, 256, 0, stream>>>(Qb, Kb, Vtg, Cb);

  k_gemm<1><<<gg, 256, 0, stream>>>(Cb, Wob, (float*)d_out);
}

// Round 9
// 252.410 us; speedup vs baseline: 1.0166x; 1.0166x over previous
//
#include <hip/hip_runtime.h>
#include <hip/hip_bf16.h>

// CrossMultiHeadAttention: B=4, N=M=2048, D=1024, H=16, hd=64, f32 in/out.
// bf16 pipeline: fused cvt -> Q-GEMM(exp2-scaled) / K-GEMM / V-GEMM(transposed epi)
// -> flash attn (XCD-affine blocks, no-max softmax, P in regs, l via ones-MFMA)
// -> out GEMM.

typedef __attribute__((ext_vector_type(8))) short bf16x8;
typedef __attribute__((ext_vector_type(4))) float f32x4;
typedef __attribute__((ext_vector_type(16))) float f32x16;
typedef __attribute__((ext_vector_type(4))) unsigned short u16x4;
typedef __attribute__((ext_vector_type(4))) unsigned int u32x4;

#define SEQ 2048
#define H_ 16

static __device__ __forceinline__ unsigned short f2bf(float f) {
  unsigned int u = __float_as_uint(f);
  u += 0x7fffu + ((u >> 16) & 1u);
  return (unsigned short)(u >> 16);
}

static __device__ __forceinline__ void gload16(const void* g, void* l) {
  __builtin_amdgcn_global_load_lds((const __attribute__((address_space(1))) void*)g,
                                   (__attribute__((address_space(3))) void*)l, 16, 0, 0);
}

// One launch converts all six f32 inputs to bf16.
__global__ __launch_bounds__(256) void k_cvt_all(const float* __restrict__ x, const float* __restrict__ e,
    const float* __restrict__ wq, const float* __restrict__ wk,
    const float* __restrict__ wv, const float* __restrict__ wo,
    unsigned short* __restrict__ Xb, unsigned short* __restrict__ Eb,
    unsigned short* __restrict__ Wqb, unsigned short* __restrict__ Wkb,
    unsigned short* __restrict__ Wvb, unsigned short* __restrict__ Wob) {
  int i = blockIdx.x * 256 + threadIdx.x;
  const float* src; unsigned short* dst; int off;
  if (i < 2097152)      { src = x;  dst = Xb;  off = i; }
  else if (i < 4194304) { src = e;  dst = Eb;  off = i - 2097152; }
  else if (i < 4456448) { src = wq; dst = Wqb; off = i - 4194304; }
  else if (i < 4718592) { src = wk; dst = Wkb; off = i - 4456448; }
  else if (i < 4980736) { src = wv; dst = Wvb; off = i - 4718592; }
  else                  { src = wo; dst = Wob; off = i - 4980736; }
  float4 v = reinterpret_cast<const float4*>(src)[off];
  u16x4 o;
  o[0] = f2bf(v.x); o[1] = f2bf(v.y); o[2] = f2bf(v.z); o[3] = f2bf(v.w);
  *reinterpret_cast<u16x4*>(dst + (size_t)off * 4) = o;
}

// C = A[R,1024] @ W[1024,1024]^T.
// MODE 0: bf16 out, [B,H,seq,64] head layout (K path).
// MODE 1: f32 out, [R,1024] (final out).
// MODE 2: like 0 but scaled by 0.125*log2(e) (Q path).
// MODE 3: bf16 out, transposed head layout [B,H,64,seq] (V path -> Vt direct).
template<int MODE>
__global__ __launch_bounds__(256) void k_gemm(const unsigned short* __restrict__ A,
                                              const unsigned short* __restrict__ W,
                                              void* __restrict__ out) {
  __shared__ __align__(16) unsigned short As[128 * 32];
  __shared__ __align__(16) unsigned short Bs[128 * 32];
  const int tid = threadIdx.x, lane = tid & 63, w = tid >> 6;
  const int col0 = blockIdx.x * 128, row0 = blockIdx.y * 128;
  const int wr = w >> 1, wc = w & 1;
  f32x4 acc[4][4];
  for (int i = 0; i < 4; ++i)
    for (int j = 0; j < 4; ++j)
      for (int e = 0; e < 4; ++e) acc[i][j][e] = 0.f;
  const unsigned short* Ag[2];
  const unsigned short* Wg[2];
  unsigned short* Al[2];
  unsigned short* Bl[2];
  for (int p = 0; p < 2; ++p) {
    int ci = p * 4 + w;
    int eo = ci * 512 + lane * 8;
    int r = eo >> 5, c = eo & 31;
    Ag[p] = A + (size_t)(row0 + r) * 1024 + c;
    Wg[p] = W + (size_t)(col0 + r) * 1024 + c;
    Al[p] = &As[ci * 512];
    Bl[p] = &Bs[ci * 512];
  }
  const int fr = lane & 15, ko = (lane >> 4) * 8;
  for (int k0 = 0; k0 < 1024; k0 += 32) {
    __syncthreads();
    for (int p = 0; p < 2; ++p) {
      gload16(Ag[p] + k0, Al[p]);
      gload16(Wg[p] + k0, Bl[p]);
    }
    __syncthreads();
    bf16x8 af[4], bfr[4];
    for (int mi = 0; mi < 4; ++mi)
      af[mi] = *(const bf16x8*)&As[(wr * 64 + mi * 16 + fr) * 32 + ko];
    for (int ni = 0; ni < 4; ++ni)
      bfr[ni] = *(const bf16x8*)&Bs[(wc * 64 + ni * 16 + fr) * 32 + ko];
    for (int mi = 0; mi < 4; ++mi)
      for (int ni = 0; ni < 4; ++ni)
        acc[mi][ni] = __builtin_amdgcn_mfma_f32_16x16x32_bf16(af[mi], bfr[ni], acc[mi][ni], 0, 0, 0);
  }
  if (MODE == 3) {
    // transposed write: Vt[((b*16+h)*64 + c)*2048 + n], j -> contiguous n
    for (int mi = 0; mi < 4; ++mi)
      for (int ni = 0; ni < 4; ++ni) {
        int r0 = row0 + wr * 64 + mi * 16 + (lane >> 4) * 4;
        int o = col0 + wc * 64 + ni * 16 + (lane & 15);
        int b = r0 >> 11, n0 = r0 & (SEQ - 1);
        int h = o >> 6, c = o & 63;
        u16x4 o4;
        for (int j = 0; j < 4; ++j) o4[j] = f2bf(acc[mi][ni][j]);
        *(u16x4*)&((unsigned short*)out)[(((size_t)(b * H_ + h)) * 64 + c) * SEQ + n0] = o4;
      }
  } else {
    for (int mi = 0; mi < 4; ++mi)
      for (int ni = 0; ni < 4; ++ni)
        for (int j = 0; j < 4; ++j) {
          int r = row0 + wr * 64 + mi * 16 + (lane >> 4) * 4 + j;
          int o = col0 + wc * 64 + ni * 16 + (lane & 15);
          float val = acc[mi][ni][j];
          if (MODE == 2) val *= 0.18033688f;   // 0.125 * log2(e)
          if (MODE == 0 || MODE == 2) {
            int b = r >> 11, n = r & (SEQ - 1);
            int h = o >> 6, c = o & 63;
            ((unsigned short*)out)[(((size_t)(b * H_ + h)) * SEQ + n) * 64 + c] = f2bf(val);
          } else {
            ((float*)out)[(size_t)r * 1024 + o] = val;
          }
        }
  }
}

static __device__ __forceinline__ int swzaddr(int row, int colb) {
  return row * 128 + (colb ^ ((row & 7) << 4));
}

// Flash attention, no-max softmax (Q pre-scaled to exp2 domain).
// Q,K in [B,H,seq,64]; Vt in [B,H,64,seq]; CTX [B*N,1024] bf16.
// 4 waves x 32 q-rows; KV tiles of 64, double-buffered (32 KB).
// 1-D grid, XCD-affine (bh,qt) decode: each XCD sees 8 heads -> K/V = 4MB = L2.
// Softmax denominator l computed on the MFMA pipe: oaccL = mfma(ones, P) gives
// every output row the full 64-key row-sum for its q column (no VALU adds,
// no cross-lane merge).
__global__ __launch_bounds__(256) void k_attn(const unsigned short* __restrict__ Qh,
                                              const unsigned short* __restrict__ Kh,
                                              const unsigned short* __restrict__ Vtg,
                                              unsigned short* __restrict__ CTX) {
  __shared__ __align__(16) char lds[4 * 8192];
  const int tid = threadIdx.x, lane = tid & 63, w = tid >> 6;
  const int hi = lane >> 5, q = lane & 31;
  const int id = blockIdx.x;
  const int bh = (id & 7) * 8 + ((id >> 3) & 7);   // XCD-affine head grouping
  const int qt = id >> 6;
  const size_t kvbase = (size_t)bh * (SEQ * 64);
  const size_t qrow = (size_t)bh * SEQ + qt * 128 + w * 32 + q;
  bf16x8 qf[4];
#pragma unroll
  for (int c = 0; c < 4; ++c)
    qf[c] = *(const bf16x8*)&Qh[qrow * 64 + c * 16 + hi * 8];
  f32x16 oacc0, oacc1, oaccL, fzero;
#pragma unroll
  for (int r = 0; r < 16; ++r) { oacc0[r] = 0.f; oacc1[r] = 0.f; oaccL[r] = 0.f; fzero[r] = 0.f; }
  bf16x8 ones;
#pragma unroll
  for (int r = 0; r < 8; ++r) ones[r] = (short)0x3F80;   // bf16 1.0

  // staging: 512 16B chunks per 8KB tile; thread handles chunks tid, tid+256.
  // LDS linear; global source pre-swizzled so reads use colb ^ ((row&7)<<4).
  size_t koff[2], voff[2];
  int ldso[2];
#pragma unroll
  for (int h = 0; h < 2; ++h) {
    int c = tid + h * 256;
    int row = c >> 3, pb = (c & 7) << 4;
    int ge = (pb ^ ((row & 7) << 4)) >> 1;
    koff[h] = (size_t)row * 64 + ge;     // + t*4096
    voff[h] = (size_t)row * SEQ + ge;    // + t*64
    ldso[h] = c * 16;
  }

#define STAGE(T, BUFO)                                          \
  {                                                             \
    _Pragma("unroll")                                           \
    for (int h = 0; h < 2; ++h) {                               \
      gload16(Kh + kvbase + (size_t)(T) * 4096 + koff[h], lds + (BUFO) + ldso[h]);        \
      gload16(Vtg + kvbase + (size_t)(T) * 64 + voff[h], lds + (BUFO) + 8192 + ldso[h]);  \
    }                                                           \
  }

  STAGE(0, 0);

  for (int t = 0; t < 32; ++t) {
    __syncthreads();  // drains vmcnt -> buf[t&1] ready, buf[t&1^1] free
    const int bo = (t & 1) * 16384;
    char* Kb = lds + bo;
    char* Vb = lds + bo + 8192;
    if (t + 1 < 32) STAGE(t + 1, ((t + 1) & 1) * 16384);

    // QK^T (swapped): s[half] = S^T[key][q], already in exp2 domain
    f32x16 s0, s1;
    __builtin_amdgcn_s_setprio(1);
    {
      bf16x8 kf0 = *(const bf16x8*)(Kb + swzaddr(q, 0 * 32 + hi * 16));
      bf16x8 kf1 = *(const bf16x8*)(Kb + swzaddr(32 + q, 0 * 32 + hi * 16));
      s0 = __builtin_amdgcn_mfma_f32_32x32x16_bf16(kf0, qf[0], fzero, 0, 0, 0);
      s1 = __builtin_amdgcn_mfma_f32_32x32x16_bf16(kf1, qf[0], fzero, 0, 0, 0);
    }
#pragma unroll
    for (int c = 1; c < 4; ++c) {
      bf16x8 kf0 = *(const bf16x8*)(Kb + swzaddr(q, c * 32 + hi * 16));
      bf16x8 kf1 = *(const bf16x8*)(Kb + swzaddr(32 + q, c * 32 + hi * 16));
      s0 = __builtin_amdgcn_mfma_f32_32x32x16_bf16(kf0, qf[c], s0, 0, 0, 0);
      s1 = __builtin_amdgcn_mfma_f32_32x32x16_bf16(kf1, qf[c], s1, 0, 0, 0);
    }
    __builtin_amdgcn_s_setprio(0);

    bf16x8 pfrag[4];

#define SOFT_PACK(SREG, FA, FB)                                               \
    {                                                                         \
      float pa[16];                                                           \
      _Pragma("unroll")                                                       \
      for (int r = 0; r < 16; ++r) pa[r] = exp2f(SREG[r]);                    \
      unsigned pw[8];                                                         \
      _Pragma("unroll")                                                       \
      for (int i = 0; i < 8; ++i)                                             \
        asm("v_cvt_pk_bf16_f32 %0, %1, %2" : "=v"(pw[i])                      \
            : "v"(pa[2 * i]), "v"(pa[2 * i + 1]));                            \
      asm("v_permlane32_swap_b32 %0, %1" : "+v"(pw[0]), "+v"(pw[2]));         \
      asm("v_permlane32_swap_b32 %0, %1" : "+v"(pw[1]), "+v"(pw[3]));         \
      asm("v_permlane32_swap_b32 %0, %1" : "+v"(pw[4]), "+v"(pw[6]));         \
      asm("v_permlane32_swap_b32 %0, %1" : "+v"(pw[5]), "+v"(pw[7]));         \
      u32x4 fa = { pw[0], pw[1], pw[2], pw[3] };                              \
      u32x4 fb = { pw[4], pw[5], pw[6], pw[7] };                              \
      FA = __builtin_bit_cast(bf16x8, fa);                                    \
      FB = __builtin_bit_cast(bf16x8, fb);                                    \
    }

    SOFT_PACK(s0, pfrag[0], pfrag[1])
    SOFT_PACK(s1, pfrag[2], pfrag[3])
#undef SOFT_PACK

    // PV: ctx^T[d][q] += Vt[d][key] * P^T[key][q]; l via ones-MFMA (row-sum)
    __builtin_amdgcn_s_setprio(1);
#pragma unroll
    for (int kk = 0; kk < 4; ++kk) {
      bf16x8 vf0 = *(const bf16x8*)(Vb + swzaddr(q, kk * 32 + hi * 16));
      bf16x8 vf1 = *(const bf16x8*)(Vb + swzaddr(32 + q, kk * 32 + hi * 16));
      oacc0 = __builtin_amdgcn_mfma_f32_32x32x16_bf16(vf0, pfrag[kk], oacc0, 0, 0, 0);
      oacc1 = __builtin_amdgcn_mfma_f32_32x32x16_bf16(vf1, pfrag[kk], oacc1, 0, 0, 0);
      oaccL = __builtin_amdgcn_mfma_f32_32x32x16_bf16(ones, pfrag[kk], oaccL, 0, 0, 0);
    }
    __builtin_amdgcn_s_setprio(0);
  }
#undef STAGE

  // epilogue: every oaccL entry = full row-sum l for this lane's q column
  const float inv = 1.0f / oaccL[0];
  const int b = bh >> 4, h = bh & 15;
  const size_t orow = ((size_t)b * SEQ + qt * 128 + w * 32 + q) * 1024 + h * 64;
#pragma unroll
  for (int g = 0; g < 4; ++g) {
    u16x4 o0, o1;
#pragma unroll
    for (int j = 0; j < 4; ++j) {
      o0[j] = f2bf(oacc0[g * 4 + j] * inv);
      o1[j] = f2bf(oacc1[g * 4 + j] * inv);
    }
    *(u16x4*)&CTX[orow + g * 8 + hi * 4] = o0;
    *(u16x4*)&CTX[orow + 32 + g * 8 + hi * 4] = o1;
  }
}

extern "C" void kernel_launch(void* const* d_in, const int* in_sizes, int n_in,
                              void* d_out, int out_size, void* d_ws, size_t ws_size,
                              hipStream_t stream) {
  const float* x  = (const float*)d_in[0];
  const float* e  = (const float*)d_in[1];
  const float* wq = (const float*)d_in[2];
  const float* wk = (const float*)d_in[3];
  const float* wv = (const float*)d_in[4];
  const float* wo = (const float*)d_in[5];
  unsigned short* Xb  = (unsigned short*)d_ws;
  unsigned short* Eb  = Xb + 8388608;
  unsigned short* Wqb = Eb + 8388608;
  unsigned short* Wkb = Wqb + 1048576;
  unsigned short* Wvb = Wkb + 1048576;
  unsigned short* Wob = Wvb + 1048576;
  unsigned short* Qb  = Wob + 1048576;
  unsigned short* Kb  = Qb + 8388608;
  unsigned short* Vtg = Kb + 8388608;   // V-GEMM writes transposed layout directly
  unsigned short* Cb  = Vtg + 8388608;

  k_cvt_all<<<20480, 256, 0, stream>>>(x, e, wq, wk, wv, wo, Xb, Eb, Wqb, Wkb, Wvb, Wob);

  dim3 gg(8, 64);
  k_gemm<2><<<gg, 256, 0, stream>>>(Xb, Wqb, Qb);   // Q, exp2-domain pre-scale
  k_gemm<0><<<gg, 256, 0, stream>>>(Eb, Wkb, Kb);
  k_gemm<3><<<gg, 256, 0, stream>>>(Eb, Wvb, Vtg);  // V, transposed epilogue

  k_attn<<<1024, 256, 0, stream>>>(Qb, Kb, Vtg, Cb);

  k_gemm<1><<<gg, 256, 0, stream>>>(Cb, Wob, (float*)d_out);
}

// Round 10
// 243.776 us; speedup vs baseline: 1.0526x; 1.0354x over previous
//
#include <hip/hip_runtime.h>
#include <hip/hip_bf16.h>

// CrossMultiHeadAttention: B=4, N=M=2048, D=1024, H=16, hd=64, f32 in/out.
// bf16 pipeline: fused cvt -> Q-GEMM(exp2-scaled) / K-GEMM / V-GEMM(transposed epi)
// -> flash attn (8-wave blocks, XCD-affine, no-max softmax, P in regs,
//    l via ones-MFMA) -> out GEMM.

typedef __attribute__((ext_vector_type(8))) short bf16x8;
typedef __attribute__((ext_vector_type(4))) float f32x4;
typedef __attribute__((ext_vector_type(16))) float f32x16;
typedef __attribute__((ext_vector_type(4))) unsigned short u16x4;
typedef __attribute__((ext_vector_type(4))) unsigned int u32x4;

#define SEQ 2048
#define H_ 16

static __device__ __forceinline__ unsigned short f2bf(float f) {
  unsigned int u = __float_as_uint(f);
  u += 0x7fffu + ((u >> 16) & 1u);
  return (unsigned short)(u >> 16);
}

static __device__ __forceinline__ void gload16(const void* g, void* l) {
  __builtin_amdgcn_global_load_lds((const __attribute__((address_space(1))) void*)g,
                                   (__attribute__((address_space(3))) void*)l, 16, 0, 0);
}

// One launch converts all six f32 inputs to bf16.
__global__ __launch_bounds__(256) void k_cvt_all(const float* __restrict__ x, const float* __restrict__ e,
    const float* __restrict__ wq, const float* __restrict__ wk,
    const float* __restrict__ wv, const float* __restrict__ wo,
    unsigned short* __restrict__ Xb, unsigned short* __restrict__ Eb,
    unsigned short* __restrict__ Wqb, unsigned short* __restrict__ Wkb,
    unsigned short* __restrict__ Wvb, unsigned short* __restrict__ Wob) {
  int i = blockIdx.x * 256 + threadIdx.x;
  const float* src; unsigned short* dst; int off;
  if (i < 2097152)      { src = x;  dst = Xb;  off = i; }
  else if (i < 4194304) { src = e;  dst = Eb;  off = i - 2097152; }
  else if (i < 4456448) { src = wq; dst = Wqb; off = i - 4194304; }
  else if (i < 4718592) { src = wk; dst = Wkb; off = i - 4456448; }
  else if (i < 4980736) { src = wv; dst = Wvb; off = i - 4718592; }
  else                  { src = wo; dst = Wob; off = i - 4980736; }
  float4 v = reinterpret_cast<const float4*>(src)[off];
  u16x4 o;
  o[0] = f2bf(v.x); o[1] = f2bf(v.y); o[2] = f2bf(v.z); o[3] = f2bf(v.w);
  *reinterpret_cast<u16x4*>(dst + (size_t)off * 4) = o;
}

// C = A[R,1024] @ W[1024,1024]^T.
// MODE 0: bf16 out, [B,H,seq,64] head layout (K path).
// MODE 1: f32 out, [R,1024] (final out).
// MODE 2: like 0 but scaled by 0.125*log2(e) (Q path).
// MODE 3: bf16 out, transposed head layout [B,H,64,seq] (V path -> Vt direct).
template<int MODE>
__global__ __launch_bounds__(256) void k_gemm(const unsigned short* __restrict__ A,
                                              const unsigned short* __restrict__ W,
                                              void* __restrict__ out) {
  __shared__ __align__(16) unsigned short As[128 * 32];
  __shared__ __align__(16) unsigned short Bs[128 * 32];
  const int tid = threadIdx.x, lane = tid & 63, w = tid >> 6;
  const int col0 = blockIdx.x * 128, row0 = blockIdx.y * 128;
  const int wr = w >> 1, wc = w & 1;
  f32x4 acc[4][4];
  for (int i = 0; i < 4; ++i)
    for (int j = 0; j < 4; ++j)
      for (int e = 0; e < 4; ++e) acc[i][j][e] = 0.f;
  const unsigned short* Ag[2];
  const unsigned short* Wg[2];
  unsigned short* Al[2];
  unsigned short* Bl[2];
  for (int p = 0; p < 2; ++p) {
    int ci = p * 4 + w;
    int eo = ci * 512 + lane * 8;
    int r = eo >> 5, c = eo & 31;
    Ag[p] = A + (size_t)(row0 + r) * 1024 + c;
    Wg[p] = W + (size_t)(col0 + r) * 1024 + c;
    Al[p] = &As[ci * 512];
    Bl[p] = &Bs[ci * 512];
  }
  const int fr = lane & 15, ko = (lane >> 4) * 8;
  for (int k0 = 0; k0 < 1024; k0 += 32) {
    __syncthreads();
    for (int p = 0; p < 2; ++p) {
      gload16(Ag[p] + k0, Al[p]);
      gload16(Wg[p] + k0, Bl[p]);
    }
    __syncthreads();
    bf16x8 af[4], bfr[4];
    for (int mi = 0; mi < 4; ++mi)
      af[mi] = *(const bf16x8*)&As[(wr * 64 + mi * 16 + fr) * 32 + ko];
    for (int ni = 0; ni < 4; ++ni)
      bfr[ni] = *(const bf16x8*)&Bs[(wc * 64 + ni * 16 + fr) * 32 + ko];
    for (int mi = 0; mi < 4; ++mi)
      for (int ni = 0; ni < 4; ++ni)
        acc[mi][ni] = __builtin_amdgcn_mfma_f32_16x16x32_bf16(af[mi], bfr[ni], acc[mi][ni], 0, 0, 0);
  }
  if (MODE == 3) {
    // transposed write: Vt[((b*16+h)*64 + c)*2048 + n], j -> contiguous n
    for (int mi = 0; mi < 4; ++mi)
      for (int ni = 0; ni < 4; ++ni) {
        int r0 = row0 + wr * 64 + mi * 16 + (lane >> 4) * 4;
        int o = col0 + wc * 64 + ni * 16 + (lane & 15);
        int b = r0 >> 11, n0 = r0 & (SEQ - 1);
        int h = o >> 6, c = o & 63;
        u16x4 o4;
        for (int j = 0; j < 4; ++j) o4[j] = f2bf(acc[mi][ni][j]);
        *(u16x4*)&((unsigned short*)out)[(((size_t)(b * H_ + h)) * 64 + c) * SEQ + n0] = o4;
      }
  } else {
    for (int mi = 0; mi < 4; ++mi)
      for (int ni = 0; ni < 4; ++ni)
        for (int j = 0; j < 4; ++j) {
          int r = row0 + wr * 64 + mi * 16 + (lane >> 4) * 4 + j;
          int o = col0 + wc * 64 + ni * 16 + (lane & 15);
          float val = acc[mi][ni][j];
          if (MODE == 2) val *= 0.18033688f;   // 0.125 * log2(e)
          if (MODE == 0 || MODE == 2) {
            int b = r >> 11, n = r & (SEQ - 1);
            int h = o >> 6, c = o & 63;
            ((unsigned short*)out)[(((size_t)(b * H_ + h)) * SEQ + n) * 64 + c] = f2bf(val);
          } else {
            ((float*)out)[(size_t)r * 1024 + o] = val;
          }
        }
  }
}

static __device__ __forceinline__ int swzaddr(int row, int colb) {
  return row * 128 + (colb ^ ((row & 7) << 4));
}

// Flash attention, no-max softmax (Q pre-scaled to exp2 domain).
// Q,K in [B,H,seq,64]; Vt in [B,H,64,seq]; CTX [B*N,1024] bf16.
// 8 waves x 32 q-rows = 256 q-rows/block (512 thr); KV tiles of 64, double-buf.
// Grid 512 = 2 blocks/CU: one resident block alone = 2 waves/SIMD, two = 4.
// XCD-affine (bh,qt) decode keeps K/V in each XCD's L2 (FETCH 139->41 MB, R8).
// l via ones-MFMA: no VALU row-sum, no cross-lane merge.
__global__ __launch_bounds__(512) void k_attn(const unsigned short* __restrict__ Qh,
                                              const unsigned short* __restrict__ Kh,
                                              const unsigned short* __restrict__ Vtg,
                                              unsigned short* __restrict__ CTX) {
  __shared__ __align__(16) char lds[4 * 8192];
  const int tid = threadIdx.x, lane = tid & 63, w = tid >> 6;
  const int hi = lane >> 5, q = lane & 31;
  const int id = blockIdx.x;
  const int bh = (id & 7) * 8 + ((id >> 3) & 7);   // XCD-affine head grouping
  const int qt = id >> 6;                          // 0..7 (256 q-rows per block)
  const size_t kvbase = (size_t)bh * (SEQ * 64);
  const size_t qrow = (size_t)bh * SEQ + qt * 256 + w * 32 + q;
  bf16x8 qf[4];
#pragma unroll
  for (int c = 0; c < 4; ++c)
    qf[c] = *(const bf16x8*)&Qh[qrow * 64 + c * 16 + hi * 8];
  f32x16 oacc0, oacc1, oaccL, fzero;
#pragma unroll
  for (int r = 0; r < 16; ++r) { oacc0[r] = 0.f; oacc1[r] = 0.f; oaccL[r] = 0.f; fzero[r] = 0.f; }
  bf16x8 ones;
#pragma unroll
  for (int r = 0; r < 8; ++r) ones[r] = (short)0x3F80;   // bf16 1.0

  // staging: 512 16B chunks per 8KB tile; each of 512 threads stages 1 K-chunk
  // and 1 V-chunk. LDS linear; global source pre-swizzled so reads use
  // colb ^ ((row&7)<<4).
  const int sc = tid;
  const int srow = sc >> 3, spb = (sc & 7) << 4;
  const int sge = (spb ^ ((srow & 7) << 4)) >> 1;
  const size_t koff = (size_t)srow * 64 + sge;   // + t*4096
  const size_t voff = (size_t)srow * SEQ + sge;  // + t*64
  const int ldso = sc * 16;

#define STAGE(T, BUFO)                                                        \
  {                                                                           \
    gload16(Kh + kvbase + (size_t)(T) * 4096 + koff, lds + (BUFO) + ldso);    \
    gload16(Vtg + kvbase + (size_t)(T) * 64 + voff, lds + (BUFO) + 8192 + ldso); \
  }

  STAGE(0, 0);

  for (int t = 0; t < 32; ++t) {
    __syncthreads();  // drains vmcnt -> buf[t&1] ready, buf[t&1^1] free
    const int bo = (t & 1) * 16384;
    char* Kb = lds + bo;
    char* Vb = lds + bo + 8192;
    if (t + 1 < 32) STAGE(t + 1, ((t + 1) & 1) * 16384);

    // QK^T (swapped): s[half] = S^T[key][q], already in exp2 domain
    f32x16 s0, s1;
    __builtin_amdgcn_s_setprio(1);
    {
      bf16x8 kf0 = *(const bf16x8*)(Kb + swzaddr(q, 0 * 32 + hi * 16));
      bf16x8 kf1 = *(const bf16x8*)(Kb + swzaddr(32 + q, 0 * 32 + hi * 16));
      s0 = __builtin_amdgcn_mfma_f32_32x32x16_bf16(kf0, qf[0], fzero, 0, 0, 0);
      s1 = __builtin_amdgcn_mfma_f32_32x32x16_bf16(kf1, qf[0], fzero, 0, 0, 0);
    }
#pragma unroll
    for (int c = 1; c < 4; ++c) {
      bf16x8 kf0 = *(const bf16x8*)(Kb + swzaddr(q, c * 32 + hi * 16));
      bf16x8 kf1 = *(const bf16x8*)(Kb + swzaddr(32 + q, c * 32 + hi * 16));
      s0 = __builtin_amdgcn_mfma_f32_32x32x16_bf16(kf0, qf[c], s0, 0, 0, 0);
      s1 = __builtin_amdgcn_mfma_f32_32x32x16_bf16(kf1, qf[c], s1, 0, 0, 0);
    }
    __builtin_amdgcn_s_setprio(0);

    bf16x8 pfrag[4];

#define SOFT_PACK(SREG, FA, FB)                                               \
    {                                                                         \
      float pa[16];                                                           \
      _Pragma("unroll")                                                       \
      for (int r = 0; r < 16; ++r) pa[r] = exp2f(SREG[r]);                    \
      unsigned pw[8];                                                         \
      _Pragma("unroll")                                                       \
      for (int i = 0; i < 8; ++i)                                             \
        asm("v_cvt_pk_bf16_f32 %0, %1, %2" : "=v"(pw[i])                      \
            : "v"(pa[2 * i]), "v"(pa[2 * i + 1]));                            \
      asm("v_permlane32_swap_b32 %0, %1" : "+v"(pw[0]), "+v"(pw[2]));         \
      asm("v_permlane32_swap_b32 %0, %1" : "+v"(pw[1]), "+v"(pw[3]));         \
      asm("v_permlane32_swap_b32 %0, %1" : "+v"(pw[4]), "+v"(pw[6]));         \
      asm("v_permlane32_swap_b32 %0, %1" : "+v"(pw[5]), "+v"(pw[7]));         \
      u32x4 fa = { pw[0], pw[1], pw[2], pw[3] };                              \
      u32x4 fb = { pw[4], pw[5], pw[6], pw[7] };                              \
      FA = __builtin_bit_cast(bf16x8, fa);                                    \
      FB = __builtin_bit_cast(bf16x8, fb);                                    \
    }

    SOFT_PACK(s0, pfrag[0], pfrag[1])
    SOFT_PACK(s1, pfrag[2], pfrag[3])
#undef SOFT_PACK

    // PV: ctx^T[d][q] += Vt[d][key] * P^T[key][q]; l via ones-MFMA (row-sum)
    __builtin_amdgcn_s_setprio(1);
#pragma unroll
    for (int kk = 0; kk < 4; ++kk) {
      bf16x8 vf0 = *(const bf16x8*)(Vb + swzaddr(q, kk * 32 + hi * 16));
      bf16x8 vf1 = *(const bf16x8*)(Vb + swzaddr(32 + q, kk * 32 + hi * 16));
      oacc0 = __builtin_amdgcn_mfma_f32_32x32x16_bf16(vf0, pfrag[kk], oacc0, 0, 0, 0);
      oacc1 = __builtin_amdgcn_mfma_f32_32x32x16_bf16(vf1, pfrag[kk], oacc1, 0, 0, 0);
      oaccL = __builtin_amdgcn_mfma_f32_32x32x16_bf16(ones, pfrag[kk], oaccL, 0, 0, 0);
    }
    __builtin_amdgcn_s_setprio(0);
  }
#undef STAGE

  // epilogue: every oaccL entry = full row-sum l for this lane's q column
  const float inv = 1.0f / oaccL[0];
  const int b = bh >> 4, h = bh & 15;
  const size_t orow = ((size_t)b * SEQ + qt * 256 + w * 32 + q) * 1024 + h * 64;
#pragma unroll
  for (int g = 0; g < 4; ++g) {
    u16x4 o0, o1;
#pragma unroll
    for (int j = 0; j < 4; ++j) {
      o0[j] = f2bf(oacc0[g * 4 + j] * inv);
      o1[j] = f2bf(oacc1[g * 4 + j] * inv);
    }
    *(u16x4*)&CTX[orow + g * 8 + hi * 4] = o0;
    *(u16x4*)&CTX[orow + 32 + g * 8 + hi * 4] = o1;
  }
}

extern "C" void kernel_launch(void* const* d_in, const int* in_sizes, int n_in,
                              void* d_out, int out_size, void* d_ws, size_t ws_size,
                              hipStream_t stream) {
  const float* x  = (const float*)d_in[0];
  const float* e  = (const float*)d_in[1];
  const float* wq = (const float*)d_in[2];
  const float* wk = (const float*)d_in[3];
  const float* wv = (const float*)d_in[4];
  const float* wo = (const float*)d_in[5];
  unsigned short* Xb  = (unsigned short*)d_ws;
  unsigned short* Eb  = Xb + 8388608;
  unsigned short* Wqb = Eb + 8388608;
  unsigned short* Wkb = Wqb + 1048576;
  unsigned short* Wvb = Wkb + 1048576;
  unsigned short* Wob = Wvb + 1048576;
  unsigned short* Qb  = Wob + 1048576;
  unsigned short* Kb  = Qb + 8388608;
  unsigned short* Vtg = Kb + 8388608;   // V-GEMM writes transposed layout directly
  unsigned short* Cb  = Vtg + 8388608;

  k_cvt_all<<<20480, 256, 0, stream>>>(x, e, wq, wk, wv, wo, Xb, Eb, Wqb, Wkb, Wvb, Wob);

  dim3 gg(8, 64);
  k_gemm<2><<<gg, 256, 0, stream>>>(Xb, Wqb, Qb);   // Q, exp2-domain pre-scale
  k_gemm<0><<<gg, 256, 0, stream>>>(Eb, Wkb, Kb);
  k_gemm<3><<<gg, 256, 0, stream>>>(Eb, Wvb, Vtg);  // V, transposed epilogue

  k_attn<<<512, 512, 0, stream>>>(Qb, Kb, Vtg, Cb);

  k_gemm<1><<<gg, 256, 0, stream>>>(Cb, Wob, (float*)d_out);
}

// Round 11
// 206.919 us; speedup vs baseline: 1.2401x; 1.1781x over previous
//
#include <hip/hip_runtime.h>
#include <hip/hip_bf16.h>

// CrossMultiHeadAttention: B=4, N=M=2048, D=1024, H=16, hd=64, f32 in/out.
// bf16 pipeline: fused cvt -> fused QKV GEMM (Q exp2-scaled, V transposed epi)
// -> flash attn (8-wave blocks, XCD-affine, no-max softmax, raw v_exp_f32,
//    P in regs, l via ones-MFMA) -> out GEMM.

typedef __attribute__((ext_vector_type(8))) short bf16x8;
typedef __attribute__((ext_vector_type(4))) float f32x4;
typedef __attribute__((ext_vector_type(16))) float f32x16;
typedef __attribute__((ext_vector_type(4))) unsigned short u16x4;
typedef __attribute__((ext_vector_type(4))) unsigned int u32x4;

#define SEQ 2048
#define H_ 16

static __device__ __forceinline__ unsigned short f2bf(float f) {
  unsigned int u = __float_as_uint(f);
  u += 0x7fffu + ((u >> 16) & 1u);
  return (unsigned short)(u >> 16);
}

static __device__ __forceinline__ void gload16(const void* g, void* l) {
  __builtin_amdgcn_global_load_lds((const __attribute__((address_space(1))) void*)g,
                                   (__attribute__((address_space(3))) void*)l, 16, 0, 0);
}

// One launch converts all six f32 inputs to bf16.
__global__ __launch_bounds__(256) void k_cvt_all(const float* __restrict__ x, const float* __restrict__ e,
    const float* __restrict__ wq, const float* __restrict__ wk,
    const float* __restrict__ wv, const float* __restrict__ wo,
    unsigned short* __restrict__ Xb, unsigned short* __restrict__ Eb,
    unsigned short* __restrict__ Wqb, unsigned short* __restrict__ Wkb,
    unsigned short* __restrict__ Wvb, unsigned short* __restrict__ Wob) {
  int i = blockIdx.x * 256 + threadIdx.x;
  const float* src; unsigned short* dst; int off;
  if (i < 2097152)      { src = x;  dst = Xb;  off = i; }
  else if (i < 4194304) { src = e;  dst = Eb;  off = i - 2097152; }
  else if (i < 4456448) { src = wq; dst = Wqb; off = i - 4194304; }
  else if (i < 4718592) { src = wk; dst = Wkb; off = i - 4456448; }
  else if (i < 4980736) { src = wv; dst = Wvb; off = i - 4718592; }
  else                  { src = wo; dst = Wob; off = i - 4980736; }
  float4 v = reinterpret_cast<const float4*>(src)[off];
  u16x4 o;
  o[0] = f2bf(v.x); o[1] = f2bf(v.y); o[2] = f2bf(v.z); o[3] = f2bf(v.w);
  *reinterpret_cast<u16x4*>(dst + (size_t)off * 4) = o;
}

// Shared GEMM core: acc = A_tile[128,1024] @ W_tile[128,1024]^T for one block.
template<typename EPI>
static __device__ __forceinline__ void gemm_core(const unsigned short* __restrict__ A,
                                                 const unsigned short* __restrict__ W,
                                                 int col0, int row0, EPI epi) {
  __shared__ __align__(16) unsigned short As[128 * 32];
  __shared__ __align__(16) unsigned short Bs[128 * 32];
  const int tid = threadIdx.x, lane = tid & 63, w = tid >> 6;
  const int wr = w >> 1, wc = w & 1;
  f32x4 acc[4][4];
  for (int i = 0; i < 4; ++i)
    for (int j = 0; j < 4; ++j)
      for (int e = 0; e < 4; ++e) acc[i][j][e] = 0.f;
  const unsigned short* Ag[2];
  const unsigned short* Wg[2];
  unsigned short* Al[2];
  unsigned short* Bl[2];
  for (int p = 0; p < 2; ++p) {
    int ci = p * 4 + w;
    int eo = ci * 512 + lane * 8;
    int r = eo >> 5, c = eo & 31;
    Ag[p] = A + (size_t)(row0 + r) * 1024 + c;
    Wg[p] = W + (size_t)(col0 + r) * 1024 + c;
    Al[p] = &As[ci * 512];
    Bl[p] = &Bs[ci * 512];
  }
  const int fr = lane & 15, ko = (lane >> 4) * 8;
  for (int k0 = 0; k0 < 1024; k0 += 32) {
    __syncthreads();
    for (int p = 0; p < 2; ++p) {
      gload16(Ag[p] + k0, Al[p]);
      gload16(Wg[p] + k0, Bl[p]);
    }
    __syncthreads();
    bf16x8 af[4], bfr[4];
    for (int mi = 0; mi < 4; ++mi)
      af[mi] = *(const bf16x8*)&As[(wr * 64 + mi * 16 + fr) * 32 + ko];
    for (int ni = 0; ni < 4; ++ni)
      bfr[ni] = *(const bf16x8*)&Bs[(wc * 64 + ni * 16 + fr) * 32 + ko];
    for (int mi = 0; mi < 4; ++mi)
      for (int ni = 0; ni < 4; ++ni)
        acc[mi][ni] = __builtin_amdgcn_mfma_f32_16x16x32_bf16(af[mi], bfr[ni], acc[mi][ni], 0, 0, 0);
  }
  for (int mi = 0; mi < 4; ++mi)
    for (int ni = 0; ni < 4; ++ni) {
      int r0 = row0 + wr * 64 + mi * 16 + (lane >> 4) * 4;
      int o = col0 + wc * 64 + ni * 16 + (lane & 15);
      epi(r0, o, acc[mi][ni]);
    }
}

// Fused Q/K/V projection GEMM; blockIdx.z selects path (block-uniform).
// z=0: Q = X@Wq^T scaled 0.125*log2(e), head layout [B,H,seq,64] bf16.
// z=1: K = E@Wk^T, head layout.
// z=2: V = E@Wv^T, transposed head layout [B,H,64,seq].
__global__ __launch_bounds__(256) void k_gemm_qkv(const unsigned short* __restrict__ Xb,
                                                  const unsigned short* __restrict__ Eb,
                                                  const unsigned short* __restrict__ Wqb,
                                                  const unsigned short* __restrict__ Wkb,
                                                  const unsigned short* __restrict__ Wvb,
                                                  unsigned short* __restrict__ Qb,
                                                  unsigned short* __restrict__ Kb,
                                                  unsigned short* __restrict__ Vtg) {
  const int z = blockIdx.z;
  const int col0 = blockIdx.x * 128, row0 = blockIdx.y * 128;
  const unsigned short* A = (z == 0) ? Xb : Eb;
  const unsigned short* W = (z == 0) ? Wqb : (z == 1) ? Wkb : Wvb;
  if (z == 2) {
    gemm_core(A, W, col0, row0, [&](int r0, int o, f32x4 v) {
      int b = r0 >> 11, n0 = r0 & (SEQ - 1);
      int h = o >> 6, c = o & 63;
      u16x4 o4;
      for (int j = 0; j < 4; ++j) o4[j] = f2bf(v[j]);
      *(u16x4*)&Vtg[(((size_t)(b * H_ + h)) * 64 + c) * SEQ + n0] = o4;
    });
  } else {
    unsigned short* out = (z == 0) ? Qb : Kb;
    const float sc = (z == 0) ? 0.18033688f : 1.0f;   // 0.125 * log2(e)
    gemm_core(A, W, col0, row0, [&](int r0, int o, f32x4 v) {
      int b = r0 >> 11, n0 = r0 & (SEQ - 1);
      int h = o >> 6, c = o & 63;
      for (int j = 0; j < 4; ++j)
        out[(((size_t)(b * H_ + h)) * SEQ + n0 + j) * 64 + c] = f2bf(v[j] * sc);
    });
  }
}

// Final GEMM: out = CTX @ Wo^T, f32 [8192,1024].
__global__ __launch_bounds__(256) void k_gemm_out(const unsigned short* __restrict__ A,
                                                  const unsigned short* __restrict__ W,
                                                  float* __restrict__ out) {
  const int col0 = blockIdx.x * 128, row0 = blockIdx.y * 128;
  gemm_core(A, W, col0, row0, [&](int r0, int o, f32x4 v) {
    for (int j = 0; j < 4; ++j)
      out[(size_t)(r0 + j) * 1024 + o] = v[j];
  });
}

static __device__ __forceinline__ int swzaddr(int row, int colb) {
  return row * 128 + (colb ^ ((row & 7) << 4));
}

// Flash attention, no-max softmax (Q pre-scaled to exp2 domain; raw v_exp_f32
// is exact for our bounded scores). Q,K in [B,H,seq,64]; Vt in [B,H,64,seq];
// CTX [B*N,1024] bf16. 8 waves x 32 q-rows = 256 q-rows/block (512 thr);
// KV tiles of 64, double-buffered. XCD-affine (bh,qt) decode keeps K/V in each
// XCD's L2 (FETCH 139->41 MB). l via ones-MFMA (no VALU row-sum/merge).
__global__ __launch_bounds__(512) void k_attn(const unsigned short* __restrict__ Qh,
                                              const unsigned short* __restrict__ Kh,
                                              const unsigned short* __restrict__ Vtg,
                                              unsigned short* __restrict__ CTX) {
  __shared__ __align__(16) char lds[4 * 8192];
  const int tid = threadIdx.x, lane = tid & 63, w = tid >> 6;
  const int hi = lane >> 5, q = lane & 31;
  const int id = blockIdx.x;
  const int bh = (id & 7) * 8 + ((id >> 3) & 7);   // XCD-affine head grouping
  const int qt = id >> 6;                          // 0..7 (256 q-rows per block)
  const size_t kvbase = (size_t)bh * (SEQ * 64);
  const size_t qrow = (size_t)bh * SEQ + qt * 256 + w * 32 + q;
  bf16x8 qf[4];
#pragma unroll
  for (int c = 0; c < 4; ++c)
    qf[c] = *(const bf16x8*)&Qh[qrow * 64 + c * 16 + hi * 8];
  f32x16 oacc0, oacc1, oaccL, fzero;
#pragma unroll
  for (int r = 0; r < 16; ++r) { oacc0[r] = 0.f; oacc1[r] = 0.f; oaccL[r] = 0.f; fzero[r] = 0.f; }
  bf16x8 ones;
#pragma unroll
  for (int r = 0; r < 8; ++r) ones[r] = (short)0x3F80;   // bf16 1.0

  // staging: 512 16B chunks per 8KB tile; each of 512 threads stages 1 K-chunk
  // and 1 V-chunk. LDS linear; global source pre-swizzled so reads use
  // colb ^ ((row&7)<<4).
  const int sc = tid;
  const int srow = sc >> 3, spb = (sc & 7) << 4;
  const int sge = (spb ^ ((srow & 7) << 4)) >> 1;
  const size_t koff = (size_t)srow * 64 + sge;   // + t*4096
  const size_t voff = (size_t)srow * SEQ + sge;  // + t*64
  const int ldso = sc * 16;

#define STAGE(T, BUFO)                                                        \
  {                                                                           \
    gload16(Kh + kvbase + (size_t)(T) * 4096 + koff, lds + (BUFO) + ldso);    \
    gload16(Vtg + kvbase + (size_t)(T) * 64 + voff, lds + (BUFO) + 8192 + ldso); \
  }

  STAGE(0, 0);

  for (int t = 0; t < 32; ++t) {
    __syncthreads();  // drains vmcnt -> buf[t&1] ready, buf[t&1^1] free
    const int bo = (t & 1) * 16384;
    char* Kb = lds + bo;
    char* Vb = lds + bo + 8192;
    if (t + 1 < 32) STAGE(t + 1, ((t + 1) & 1) * 16384);

    // QK^T (swapped): s[half] = S^T[key][q], already in exp2 domain
    f32x16 s0, s1;
    __builtin_amdgcn_s_setprio(1);
    {
      bf16x8 kf0 = *(const bf16x8*)(Kb + swzaddr(q, 0 * 32 + hi * 16));
      bf16x8 kf1 = *(const bf16x8*)(Kb + swzaddr(32 + q, 0 * 32 + hi * 16));
      s0 = __builtin_amdgcn_mfma_f32_32x32x16_bf16(kf0, qf[0], fzero, 0, 0, 0);
      s1 = __builtin_amdgcn_mfma_f32_32x32x16_bf16(kf1, qf[0], fzero, 0, 0, 0);
    }
#pragma unroll
    for (int c = 1; c < 4; ++c) {
      bf16x8 kf0 = *(const bf16x8*)(Kb + swzaddr(q, c * 32 + hi * 16));
      bf16x8 kf1 = *(const bf16x8*)(Kb + swzaddr(32 + q, c * 32 + hi * 16));
      s0 = __builtin_amdgcn_mfma_f32_32x32x16_bf16(kf0, qf[c], s0, 0, 0, 0);
      s1 = __builtin_amdgcn_mfma_f32_32x32x16_bf16(kf1, qf[c], s1, 0, 0, 0);
    }
    __builtin_amdgcn_s_setprio(0);

    bf16x8 pfrag[4];

#define SOFT_PACK(SREG, FA, FB)                                               \
    {                                                                         \
      float pa[16];                                                           \
      _Pragma("unroll")                                                       \
      for (int r = 0; r < 16; ++r) pa[r] = __builtin_amdgcn_exp2f(SREG[r]);   \
      unsigned pw[8];                                                         \
      _Pragma("unroll")                                                       \
      for (int i = 0; i < 8; ++i)                                             \
        asm("v_cvt_pk_bf16_f32 %0, %1, %2" : "=v"(pw[i])                      \
            : "v"(pa[2 * i]), "v"(pa[2 * i + 1]));                            \
      asm("v_permlane32_swap_b32 %0, %1" : "+v"(pw[0]), "+v"(pw[2]));         \
      asm("v_permlane32_swap_b32 %0, %1" : "+v"(pw[1]), "+v"(pw[3]));         \
      asm("v_permlane32_swap_b32 %0, %1" : "+v"(pw[4]), "+v"(pw[6]));         \
      asm("v_permlane32_swap_b32 %0, %1" : "+v"(pw[5]), "+v"(pw[7]));         \
      u32x4 fa = { pw[0], pw[1], pw[2], pw[3] };                              \
      u32x4 fb = { pw[4], pw[5], pw[6], pw[7] };                              \
      FA = __builtin_bit_cast(bf16x8, fa);                                    \
      FB = __builtin_bit_cast(bf16x8, fb);                                    \
    }

    SOFT_PACK(s0, pfrag[0], pfrag[1])
    SOFT_PACK(s1, pfrag[2], pfrag[3])
#undef SOFT_PACK

    // PV: ctx^T[d][q] += Vt[d][key] * P^T[key][q]; l via ones-MFMA (row-sum)
    __builtin_amdgcn_s_setprio(1);
#pragma unroll
    for (int kk = 0; kk < 4; ++kk) {
      bf16x8 vf0 = *(const bf16x8*)(Vb + swzaddr(q, kk * 32 + hi * 16));
      bf16x8 vf1 = *(const bf16x8*)(Vb + swzaddr(32 + q, kk * 32 + hi * 16));
      oacc0 = __builtin_amdgcn_mfma_f32_32x32x16_bf16(vf0, pfrag[kk], oacc0, 0, 0, 0);
      oacc1 = __builtin_amdgcn_mfma_f32_32x32x16_bf16(vf1, pfrag[kk], oacc1, 0, 0, 0);
      oaccL = __builtin_amdgcn_mfma_f32_32x32x16_bf16(ones, pfrag[kk], oaccL, 0, 0, 0);
    }
    __builtin_amdgcn_s_setprio(0);
  }
#undef STAGE

  // epilogue: every oaccL entry = full row-sum l for this lane's q column
  const float inv = 1.0f / oaccL[0];
  const int b = bh >> 4, h = bh & 15;
  const size_t orow = ((size_t)b * SEQ + qt * 256 + w * 32 + q) * 1024 + h * 64;
#pragma unroll
  for (int g = 0; g < 4; ++g) {
    u16x4 o0, o1;
#pragma unroll
    for (int j = 0; j < 4; ++j) {
      o0[j] = f2bf(oacc0[g * 4 + j] * inv);
      o1[j] = f2bf(oacc1[g * 4 + j] * inv);
    }
    *(u16x4*)&CTX[orow + g * 8 + hi * 4] = o0;
    *(u16x4*)&CTX[orow + 32 + g * 8 + hi * 4] = o1;
  }
}

extern "C" void kernel_launch(void* const* d_in, const int* in_sizes, int n_in,
                              void* d_out, int out_size, void* d_ws, size_t ws_size,
                              hipStream_t stream) {
  const float* x  = (const float*)d_in[0];
  const float* e  = (const float*)d_in[1];
  const float* wq = (const float*)d_in[2];
  const float* wk = (const float*)d_in[3];
  const float* wv = (const float*)d_in[4];
  const float* wo = (const float*)d_in[5];
  unsigned short* Xb  = (unsigned short*)d_ws;
  unsigned short* Eb  = Xb + 8388608;
  unsigned short* Wqb = Eb + 8388608;
  unsigned short* Wkb = Wqb + 1048576;
  unsigned short* Wvb = Wkb + 1048576;
  unsigned short* Wob = Wvb + 1048576;
  unsigned short* Qb  = Wob + 1048576;
  unsigned short* Kb  = Qb + 8388608;
  unsigned short* Vtg = Kb + 8388608;   // V-GEMM writes transposed layout directly
  unsigned short* Cb  = Vtg + 8388608;

  k_cvt_all<<<20480, 256, 0, stream>>>(x, e, wq, wk, wv, wo, Xb, Eb, Wqb, Wkb, Wvb, Wob);

  k_gemm_qkv<<<dim3(8, 64, 3), 256, 0, stream>>>(Xb, Eb, Wqb, Wkb, Wvb, Qb, Kb, Vtg);

  k_attn<<<512, 512, 0, stream>>>(Qb, Kb, Vtg, Cb);

  k_gemm_out<<<dim3(8, 64), 256, 0, stream>>>(Cb, Wob, (float*)d_out);
}